// Round 2
// baseline (20976.384 us; speedup 1.0000x reference)
//
#include <hip/hip_runtime.h>
#include <hip/hip_bf16.h>

#define NB 32      // batch
#define NS 256     // seq len
#define NI 1024    // input size
#define NO 1024    // hidden size
#define NK 2048    // NI + NO
#define NC 4096    // 4 * NO
#define NBLK 256   // persistent blocks
#define LN_EPS 1e-5f

typedef __attribute__((ext_vector_type(4))) float f32x4;
typedef __attribute__((ext_vector_type(4))) unsigned int u32x4;

__device__ __forceinline__ f32x4 mfma_bf16_16x16x32(u32x4 a, u32x4 b, f32x4 c) {
  asm volatile("v_mfma_f32_16x16x32_bf16 %0, %1, %2, %0" : "+v"(c) : "v"(a), "v"(b));
  return c;
}

__device__ __forceinline__ float sigf(float x) { return 1.0f / (1.0f + __expf(-x)); }

// 2-level grid barrier: 16 groups x 16 blocks -> root. Monotone epochs, no reset.
__device__ __forceinline__ void gbar(int* __restrict__ barr, int b, int epoch) {
  __syncthreads();
  __threadfence();                       // release: drain this block's writes
  if (threadIdx.x == 0) {
    int* cnt1 = barr + (b >> 4) * 16;    // 16 counters, 64B apart
    int* cnt2 = barr + 256;
    int* rel  = barr + 272;
    int v = __hip_atomic_fetch_add(cnt1, 1, __ATOMIC_RELAXED, __HIP_MEMORY_SCOPE_AGENT);
    bool done = false;
    if (v == epoch * 16 - 1) {           // last of group -> arrive at root
      int v2 = __hip_atomic_fetch_add(cnt2, 1, __ATOMIC_RELAXED, __HIP_MEMORY_SCOPE_AGENT);
      if (v2 == epoch * 16 - 1) {
        __hip_atomic_store(rel, epoch, __ATOMIC_RELAXED, __HIP_MEMORY_SCOPE_AGENT);
        done = true;
      }
    }
    if (!done) {
      while (__hip_atomic_load(rel, __ATOMIC_RELAXED, __HIP_MEMORY_SCOPE_AGENT) < epoch)
        __builtin_amdgcn_s_sleep(1);
    }
  }
  __syncthreads();
  __threadfence();                       // acquire side
}

// ---------------- setup kernels ----------------

__global__ void convert_x(const float* __restrict__ x, __hip_bfloat16* __restrict__ xbf) {
  size_t i = ((size_t)blockIdx.x * 256 + threadIdx.x) * 4;
  float4 v = *(const float4*)(x + i);
  xbf[i + 0] = __float2bfloat16(v.x);
  xbf[i + 1] = __float2bfloat16(v.y);
  xbf[i + 2] = __float2bfloat16(v.z);
  xbf[i + 3] = __float2bfloat16(v.w);
}

// W (fp32, [k=2048][n=4096]) -> WT bf16 [n][k]
__global__ void transpose_w(const float* __restrict__ W, __hip_bfloat16* __restrict__ WT) {
  __shared__ float tile[64][65];
  const int b  = blockIdx.x;
  const int k0 = (b & 31) * 64;
  const int n0 = (b >> 5) * 64;
  const int tid = threadIdx.x;
  const int r = tid >> 6;
  const int c = tid & 63;
#pragma unroll
  for (int i = 0; i < 16; ++i) {
    const int rr = i * 4 + r;
    tile[rr][c] = W[(size_t)(k0 + rr) * NC + n0 + c];
  }
  __syncthreads();
#pragma unroll
  for (int i = 0; i < 16; ++i) {
    const int rr = i * 4 + r;
    WT[(size_t)(n0 + rr) * NK + k0 + c] = __float2bfloat16(tile[c][rr]);
  }
}

__global__ void init_state(const float* __restrict__ hx0, const float* __restrict__ cx0,
                           __hip_bfloat16* __restrict__ hbf, float* __restrict__ cst,
                           float* __restrict__ hf, int* __restrict__ barr) {
  const int i = blockIdx.x * 256 + threadIdx.x;  // 32768 = NB*NO
  const int j = i & (NO - 1);
  const float hv = hx0[j];
  hbf[i] = __float2bfloat16(hv);
  hf[i]  = hv;
  cst[i] = cx0[j];
  if (blockIdx.x == 0) {
    barr[threadIdx.x] = 0;
    if (threadIdx.x < 64) barr[256 + threadIdx.x] = 0;
  }
}

// ---------------- persistent fused LSTM kernel ----------------
// Block b owns j-cols [4b,4b+4) x 4 gates = 16 n-cols. B-slice (16x2048 bf16
// = 64KB) pinned in LDS in MFMA-fragment order. 4 waves split K (512 each);
// K-partials exchanged via L1-hot global scratch. LN stats: per-block row
// partials -> grid barrier -> waves 0,1 reduce 256 blocks -> gates; c in regs.
__global__ __launch_bounds__(256)
void lstm_fused(const __hip_bfloat16* __restrict__ xbf,
                __hip_bfloat16* __restrict__ hbf,
                const __hip_bfloat16* __restrict__ WT,
                const float* __restrict__ bias,
                const float* __restrict__ gamma,
                const float* __restrict__ beta,
                const float* __restrict__ cx0,
                float* __restrict__ out,
                float* __restrict__ Sbuf,     // [32][256]
                float* __restrict__ SSbuf,    // [32][256]
                float* __restrict__ xchg,     // [256][4][2][256]
                float* __restrict__ combsm,   // [256][32][16]
                int* __restrict__ barr) {
  __shared__ __align__(16) __hip_bfloat16 Bs[16 * 2048];   // 64KB exactly
  const int b   = blockIdx.x;
  const int tid = threadIdx.x;
  const int j0  = b * 4;

  // ---- stage B into LDS, fragment order: f = kt*64 + q*16 + c ----
#pragma unroll
  for (int i = 0; i < 16; ++i) {
    int f  = i * 256 + tid;
    int kt = f >> 6, q = (f >> 4) & 3, c = f & 15;
    int n  = (c >> 2) * 1024 + j0 + (c & 3);
    *(u32x4*)(Bs + (size_t)f * 8) =
        *(const u32x4*)(WT + (size_t)n * NK + kt * 32 + q * 8);
  }

  const int wv = tid >> 6, l = tid & 63, q = l >> 4, ln = l & 15;

  // reduction-thread constants: (row, col-pair)
  const int r_row = tid >> 3, r_c0 = (tid & 7) * 2;
  const int r_n0 = ((r_c0 >> 2) << 10) + j0 + (r_c0 & 3);
  const int r_n1 = (((r_c0 + 1) >> 2) << 10) + j0 + ((r_c0 + 1) & 3);
  const float bias0 = bias[r_n0], bias1 = bias[r_n1];
  const int r_mt = r_row >> 4, r_rr = r_row & 15;
  const int r_idx0 = ((r_rr >> 2) * 16 + r_c0) * 4 + (r_rr & 3);
  const int r_idx1 = ((r_rr >> 2) * 16 + r_c0 + 1) * 4 + (r_rr & 3);

  // gate-thread constants (tid < 128): element (m=tid>>2, j=j0+(tid&3))
  const int g_m = tid >> 2, g_j = tid & 3;
  float g_gam[4], g_bet[4], c_reg = 0.f;
  if (tid < 128) {
#pragma unroll
    for (int g = 0; g < 4; ++g) {
      g_gam[g] = gamma[g * 1024 + j0 + g_j];
      g_bet[g] = beta[g * 1024 + j0 + g_j];
    }
    c_reg = cx0[j0 + g_j];
  }

  float* xch = xchg + (size_t)b * 2048;
  __syncthreads();

  int ep = 0;
  for (int t = 0; t < NS; ++t) {
    // ---- phase 1: GEMM (wave wv covers K in [wv*512, wv*512+512)) ----
    const __hip_bfloat16* a0p;
    const __hip_bfloat16* a1p;
    if (wv < 2) {
      a0p = xbf + ((size_t)ln * NS + t) * NI + wv * 512 + q * 8;
      a1p = xbf + ((size_t)(ln + 16) * NS + t) * NI + wv * 512 + q * 8;
    } else {
      a0p = hbf + (size_t)ln * NO + (wv - 2) * 512 + q * 8;
      a1p = hbf + (size_t)(ln + 16) * NO + (wv - 2) * 512 + q * 8;
    }
    f32x4 acc0 = {0.f, 0.f, 0.f, 0.f}, acc1 = {0.f, 0.f, 0.f, 0.f};
    asm volatile("s_nop 1" ::);
#pragma unroll
    for (int i = 0; i < 16; ++i) {
      u32x4 a0 = *(const u32x4*)(a0p + i * 32);
      u32x4 a1 = *(const u32x4*)(a1p + i * 32);
      u32x4 bb = *(const u32x4*)(Bs + ((size_t)wv * 1024 + i * 64 + l) * 8);
      acc0 = mfma_bf16_16x16x32(a0, bb, acc0);
      acc1 = mfma_bf16_16x16x32(a1, bb, acc1);
    }
    asm volatile("s_nop 7\n\ts_nop 7" ::);
    *(f32x4*)(xch + wv * 512 + l * 4)       = acc0;   // (wv, mt=0), lane-major
    *(f32x4*)(xch + wv * 512 + 256 + l * 4) = acc1;   // (wv, mt=1)
    __syncthreads();

    // ---- reduce K-partials + bias; per-row (sum, sumsq) partials ----
    float v0 = bias0, v1 = bias1;
    {
      const float* xr = xch + r_mt * 256;
#pragma unroll
      for (int w = 0; w < 4; ++w) {
        v0 += xr[w * 512 + r_idx0];
        v1 += xr[w * 512 + r_idx1];
      }
    }
    combsm[((size_t)b * 32 + r_row) * 16 + r_c0]     = v0;
    combsm[((size_t)b * 32 + r_row) * 16 + r_c0 + 1] = v1;
    float s = v0 + v1, ss = v0 * v0 + v1 * v1;
    s += __shfl_xor(s, 1);  ss += __shfl_xor(ss, 1);
    s += __shfl_xor(s, 2);  ss += __shfl_xor(ss, 2);
    s += __shfl_xor(s, 4);  ss += __shfl_xor(ss, 4);
    if ((tid & 7) == 0) {
      Sbuf[r_row * 256 + b]  = s;
      SSbuf[r_row * 256 + b] = ss;
    }
    gbar(barr, b, ++ep);

    // ---- phase 2: global LN stats + gates + state update ----
    if (tid < 128) {   // waves 0,1 exactly
      const int row   = wv * 16 + ln;  // 0..31
      const int chunk = q;             // 4 chunks of 64 blocks
      float s2 = 0.f, ss2 = 0.f;
      const float* sp  = Sbuf  + row * 256 + chunk * 64;
      const float* ssp = SSbuf + row * 256 + chunk * 64;
#pragma unroll
      for (int i = 0; i < 16; ++i) {
        f32x4 va = *(const f32x4*)(sp + i * 4);
        f32x4 vb = *(const f32x4*)(ssp + i * 4);
        s2  += va[0] + va[1] + va[2] + va[3];
        ss2 += vb[0] + vb[1] + vb[2] + vb[3];
      }
      s2 += __shfl_xor(s2, 16);  ss2 += __shfl_xor(ss2, 16);
      s2 += __shfl_xor(s2, 32);  ss2 += __shfl_xor(ss2, 32);
      const float mean = s2 * (1.f / 4096.f);
      const float var  = ss2 * (1.f / 4096.f) - mean * mean;
      const float rstd = rsqrtf(var + LN_EPS);
      // thread (g_m, g_j) fetches stats for row g_m: held by lane (l>>2)
      const float mym = __shfl(mean, l >> 2);
      const float myr = __shfl(rstd, l >> 2);
      const float* cm = combsm + ((size_t)b * 32 + g_m) * 16 + g_j;
      const float iv = (cm[0]  - mym) * myr * g_gam[0] + g_bet[0];
      const float fv = (cm[4]  - mym) * myr * g_gam[1] + g_bet[1];
      const float gv = (cm[8]  - mym) * myr * g_gam[2] + g_bet[2];
      const float ov = (cm[12] - mym) * myr * g_gam[3] + g_bet[3];
      c_reg = sigf(fv) * c_reg + sigf(iv) * tanhf(gv);
      const float hh = sigf(ov) * c_reg;
      out[((size_t)g_m * NS + t) * NO + j0 + g_j] = hh;
      hbf[(size_t)g_m * NO + j0 + g_j] = __float2bfloat16(hh);
    }
    gbar(barr, b, ++ep);
  }
}

// ---------------- fallback (small ws): round-1 fp32 path ----------------

__launch_bounds__(256)
__global__ void step_gemm_f32(const float* __restrict__ x, const float* __restrict__ hf,
                              const float* __restrict__ W, const float* __restrict__ bias,
                              float* __restrict__ comb, float* __restrict__ partials,
                              int t) {
  const int blk = blockIdx.x;
  const int tid = threadIdx.x;
  const int n   = blk * 16 + (tid & 15);
  const int mlo = tid >> 4;
  float a0 = 0.f, a1 = 0.f;
  for (int k = 0; k < NI; ++k) {
    const float wv = W[(size_t)k * NC + n];
    a0 += x[((size_t)mlo * NS + t) * NI + k] * wv;
    a1 += x[((size_t)(mlo + 16) * NS + t) * NI + k] * wv;
  }
  for (int k = 0; k < NO; ++k) {
    const float wv = W[(size_t)(NI + k) * NC + n];
    a0 += hf[mlo * NO + k] * wv;
    a1 += hf[(mlo + 16) * NO + k] * wv;
  }
  a0 += bias[n];
  a1 += bias[n];
  comb[(size_t)mlo * NC + n] = a0;
  comb[(size_t)(mlo + 16) * NC + n] = a1;
  __shared__ float sred[32][16], ssred[32][16];
  sred[mlo][tid & 15] = a0;        ssred[mlo][tid & 15] = a0 * a0;
  sred[mlo + 16][tid & 15] = a1;   ssred[mlo + 16][tid & 15] = a1 * a1;
  __syncthreads();
  if (tid < 32) {
    float s = 0.f, ss = 0.f;
    for (int i = 0; i < 16; ++i) { s += sred[tid][i]; ss += ssred[tid][i]; }
    partials[((size_t)blk * 32 + tid) * 2 + 0] = s;
    partials[((size_t)blk * 32 + tid) * 2 + 1] = ss;
  }
}

__launch_bounds__(256)
__global__ void step_update(const float* __restrict__ comb,
                            const float* __restrict__ partials,
                            const float* __restrict__ gamma,
                            const float* __restrict__ beta,
                            float* __restrict__ cst,
                            float* __restrict__ out,
                            __hip_bfloat16* __restrict__ hbf,
                            float* __restrict__ hf,
                            int t) {
  __shared__ float red[32][8][2];
  __shared__ float stat[32][2];
  const int tid = threadIdx.x;
  const int m   = tid >> 3;
  const int i8  = tid & 7;
  float s = 0.f, ss = 0.f;
  for (int i = 0; i < 32; ++i) {
    const int w = i8 * 32 + i;
    s  += partials[((size_t)w * 32 + m) * 2 + 0];
    ss += partials[((size_t)w * 32 + m) * 2 + 1];
  }
  red[m][i8][0] = s;
  red[m][i8][1] = ss;
  __syncthreads();
  if (i8 == 0) {
    for (int i = 1; i < 8; ++i) { s += red[m][i][0]; ss += red[m][i][1]; }
    const float mean = s * (1.f / NC);
    const float var  = ss * (1.f / NC) - mean * mean;
    stat[m][0] = mean;
    stat[m][1] = rsqrtf(var + LN_EPS);
  }
  __syncthreads();
  const float mean = stat[m][0];
  const float rs   = stat[m][1];
  const int jj = blockIdx.x * 32 + i8 * 4;
#pragma unroll
  for (int e = 0; e < 4; ++e) {
    const int j = jj + e;
    const float iv = (comb[(size_t)m * NC + j]          - mean) * rs * gamma[j]          + beta[j];
    const float fv = (comb[(size_t)m * NC + NO + j]     - mean) * rs * gamma[NO + j]     + beta[NO + j];
    const float gv = (comb[(size_t)m * NC + 2 * NO + j] - mean) * rs * gamma[2 * NO + j] + beta[2 * NO + j];
    const float ov = (comb[(size_t)m * NC + 3 * NO + j] - mean) * rs * gamma[3 * NO + j] + beta[3 * NO + j];
    const float cc = sigf(fv) * cst[m * NO + j] + sigf(iv) * tanhf(gv);
    const float hh = sigf(ov) * cc;
    cst[m * NO + j] = cc;
    out[((size_t)m * NS + t) * NO + j] = hh;
    hf[m * NO + j]  = hh;
    hbf[m * NO + j] = __float2bfloat16(hh);
  }
}

// ---------------- launch ----------------

extern "C" void kernel_launch(void* const* d_in, const int* in_sizes, int n_in,
                              void* d_out, int out_size, void* d_ws, size_t ws_size,
                              hipStream_t stream) {
  (void)in_sizes; (void)n_in; (void)out_size;
  const float* x     = (const float*)d_in[0];
  const float* W     = (const float*)d_in[1];
  const float* bias  = (const float*)d_in[2];
  const float* gamma = (const float*)d_in[3];
  const float* beta  = (const float*)d_in[4];
  const float* hx0   = (const float*)d_in[5];
  const float* cx0   = (const float*)d_in[6];
  float* outp = (float*)d_out;

  char* ws = (char*)d_ws;
  size_t off = 0;
  auto alloc = [&](size_t bytes) -> char* {
    off = (off + 255) & ~(size_t)255;
    char* p = ws + off;
    off += bytes;
    return p;
  };
  int*   barr          = (int*)alloc(320 * 4);
  float* Sbuf          = (float*)alloc((size_t)32 * 256 * 4);
  float* SSbuf         = (float*)alloc((size_t)32 * 256 * 4);
  float* xchg          = (float*)alloc((size_t)NBLK * 2048 * 4);
  float* combsm        = (float*)alloc((size_t)NBLK * 32 * 16 * 4);
  __hip_bfloat16* hbf  = (__hip_bfloat16*)alloc((size_t)NB * NO * 2);
  float* cst           = (float*)alloc((size_t)NB * NO * 4);
  float* hf            = (float*)alloc((size_t)NB * NO * 4);
  float* comb          = (float*)alloc((size_t)NB * NC * 4);
  float* partials      = (float*)alloc((size_t)256 * 32 * 2 * 4);
  __hip_bfloat16* xbf  = (__hip_bfloat16*)alloc((size_t)NB * NS * NI * 2);
  __hip_bfloat16* WT   = (__hip_bfloat16*)alloc((size_t)NC * NK * 2);
  const bool big = (ws_size >= off);

  hipLaunchKernelGGL(init_state, dim3((NB * NO) / 256), dim3(256), 0, stream,
                     hx0, cx0, hbf, cst, hf, barr);
  if (big) {
    hipLaunchKernelGGL(convert_x, dim3((NB * NS * NI) / (256 * 4)), dim3(256), 0, stream,
                       x, xbf);
    hipLaunchKernelGGL(transpose_w, dim3((NK / 64) * (NC / 64)), dim3(256), 0, stream,
                       W, WT);
    const __hip_bfloat16* xbf_c = xbf;
    const __hip_bfloat16* WT_c  = WT;
    void* kargs[] = {(void*)&xbf_c, (void*)&hbf, (void*)&WT_c, (void*)&bias,
                     (void*)&gamma, (void*)&beta, (void*)&cx0, (void*)&outp,
                     (void*)&Sbuf, (void*)&SSbuf, (void*)&xchg, (void*)&combsm,
                     (void*)&barr};
    hipLaunchCooperativeKernel((const void*)lstm_fused, dim3(NBLK), dim3(256),
                               kargs, 0, stream);
  } else {
    for (int t = 0; t < NS; ++t) {
      hipLaunchKernelGGL(step_gemm_f32, dim3(256), dim3(256), 0, stream,
                         x, hf, W, bias, comb, partials, t);
      hipLaunchKernelGGL(step_update, dim3(32), dim3(256), 0, stream,
                         comb, partials, gamma, beta, cst, outp, hbf, hf, t);
    }
  }
}

// Round 3
// 3077.795 us; speedup vs baseline: 6.8154x; 6.8154x over previous
//
#include <hip/hip_runtime.h>
#include <hip/hip_bf16.h>

#define NB 32      // batch
#define NS 256     // seq len
#define NI 1024    // input size
#define NO 1024    // hidden size
#define NK 2048    // NI + NO
#define NC 4096    // 4 * NO
#define LN_EPS 1e-5f

typedef __attribute__((ext_vector_type(4))) float f32x4;
typedef __attribute__((ext_vector_type(4))) unsigned int u32x4;

__device__ __forceinline__ f32x4 mfma_bf16_16x16x32(u32x4 a, u32x4 b, f32x4 c) {
  asm volatile("v_mfma_f32_16x16x32_bf16 %0, %1, %2, %0" : "+v"(c) : "v"(a), "v"(b));
  return c;
}

__device__ __forceinline__ float sigf(float x) { return 1.0f / (1.0f + __expf(-x)); }

// ---------------- setup kernels ----------------

// x (fp32, B*S*NI) -> bf16, same layout [m][t][k]
__global__ void convert_x(const float* __restrict__ x, __hip_bfloat16* __restrict__ xbf) {
  size_t i = ((size_t)blockIdx.x * 256 + threadIdx.x) * 4;
  float4 v = *(const float4*)(x + i);
  xbf[i + 0] = __float2bfloat16(v.x);
  xbf[i + 1] = __float2bfloat16(v.y);
  xbf[i + 2] = __float2bfloat16(v.z);
  xbf[i + 3] = __float2bfloat16(v.w);
}

// W fp32 [k=2048][n=4096] -> WF bf16 in MFMA-fragment order.
// Block b of the GEMM owns interleaved cols n(c) = (c>>2)*1024 + b*4 + (c&3),
// c=0..15 (round-2 verified mapping). Fragment for (b, kt, lane l=(q,ln)):
// WF[((b*64+kt)*64 + l)*8 + j] = W[kt*32 + q*8 + j][n(ln&15)], j=0..7.
// grid 16384 = 256 b * 64 kt, 64 threads.
__global__ void pack_wf(const float* __restrict__ W, __hip_bfloat16* __restrict__ WF) {
  const int blk = blockIdx.x;
  const int b = blk >> 6, kt = blk & 63;
  const int l = threadIdx.x, q = l >> 4, c = l & 15;
  const int n  = ((c >> 2) << 10) + b * 4 + (c & 3);
  const int k0 = kt * 32 + q * 8;
  __align__(16) __hip_bfloat16 tmp[8];
#pragma unroll
  for (int j = 0; j < 8; ++j)
    tmp[j] = __float2bfloat16(W[(size_t)(k0 + j) * NC + n]);
  *(u32x4*)(WF + ((size_t)(b * 64 + kt) * 64 + l) * 8) = *(const u32x4*)tmp;
}

// init h (bf16 + fp32) and c from init_hx/init_cx (broadcast row 0)
__global__ void init_state(const float* __restrict__ hx0, const float* __restrict__ cx0,
                           __hip_bfloat16* __restrict__ hbf, float* __restrict__ cst,
                           float* __restrict__ hf) {
  const int i = blockIdx.x * 256 + threadIdx.x;  // 32768 = NB*NO
  const int j = i & (NO - 1);
  const float hv = hx0[j];
  hbf[i] = __float2bfloat16(hv);
  hf[i]  = hv;
  cst[i] = cx0[j];
}

// ---------------- per-step kernel A: MFMA GEMM ----------------
// grid 256 x 256 (4 waves). Block b owns the 16 interleaved n-cols above.
// Waves split K 4x512; B frags streamed straight from WF (contiguous 16B per
// lane); K-partials reduced via 8KB LDS; writes comb[32][4096] fp32 + bias.
__global__ __launch_bounds__(256)
void step_gemm_mfma(const __hip_bfloat16* __restrict__ xbf,
                    const __hip_bfloat16* __restrict__ hbf,
                    const __hip_bfloat16* __restrict__ WF,
                    const float* __restrict__ bias,
                    float* __restrict__ comb, int t) {
  __shared__ __align__(16) float xch[4 * 2 * 256];
  const int b = blockIdx.x, tid = threadIdx.x;
  const int wv = tid >> 6, l = tid & 63, q = l >> 4, ln = l & 15;

  const __hip_bfloat16* a0p;
  const __hip_bfloat16* a1p;
  if (wv < 2) {
    a0p = xbf + ((size_t)ln * NS + t) * NI + wv * 512 + q * 8;
    a1p = xbf + ((size_t)(ln + 16) * NS + t) * NI + wv * 512 + q * 8;
  } else {
    a0p = hbf + (size_t)ln * NO + (wv - 2) * 512 + q * 8;
    a1p = hbf + (size_t)(ln + 16) * NO + (wv - 2) * 512 + q * 8;
  }
  const __hip_bfloat16* bp = WF + ((size_t)(b * 64 + wv * 16) * 64 + l) * 8;

  f32x4 acc0 = {0.f, 0.f, 0.f, 0.f}, acc1 = {0.f, 0.f, 0.f, 0.f};
  asm volatile("s_nop 1" ::);  // VALU-write(acc init) -> MFMA-read-C hazard
#pragma unroll
  for (int i = 0; i < 16; ++i) {
    u32x4 a0 = *(const u32x4*)(a0p + i * 32);
    u32x4 a1 = *(const u32x4*)(a1p + i * 32);
    u32x4 bb = *(const u32x4*)(bp + (size_t)i * 512);  // next kt: 64 lanes * 8
    acc0 = mfma_bf16_16x16x32(a0, bb, acc0);
    acc1 = mfma_bf16_16x16x32(a1, bb, acc1);
  }
  asm volatile("s_nop 7\n\ts_nop 7" ::);  // MFMA-write -> VALU-read hazard

  // D layout: col=ln, row=q*4+r. Store per-wave partials, reduce across waves.
  *(f32x4*)(xch + wv * 512 + l * 4)       = acc0;  // mt=0 rows 0..15
  *(f32x4*)(xch + wv * 512 + 256 + l * 4) = acc1;  // mt=1 rows 16..31
  __syncthreads();

  const int r_row = tid >> 3, r_c0 = (tid & 7) * 2;   // row 0..31, col pair
  const int r_mt = r_row >> 4, r_rr = r_row & 15;
  const int r_idx0 = ((r_rr >> 2) * 16 + r_c0) * 4 + (r_rr & 3);
  const int r_idx1 = ((r_rr >> 2) * 16 + r_c0 + 1) * 4 + (r_rr & 3);
  const int n0 = ((r_c0 >> 2) << 10) + b * 4 + (r_c0 & 3);  // n1 = n0+1 always
  float v0 = bias[n0], v1 = bias[n0 + 1];
  const float* xr = xch + r_mt * 256;
#pragma unroll
  for (int w = 0; w < 4; ++w) {
    v0 += xr[w * 512 + r_idx0];
    v1 += xr[w * 512 + r_idx1];
  }
  float2 vv = {v0, v1};
  *(float2*)(comb + (size_t)r_row * NC + n0) = vv;
}

// ---------------- per-step kernel B: LN + gates + state ----------------
// grid 32 x 1024. Block = batch row m. Reads comb row (16KB) coalesced,
// block-local LN stats, gates, c/h update. No partials buffer.
__global__ __launch_bounds__(1024)
void step_update_row(const float* __restrict__ comb,
                     const float* __restrict__ gamma,
                     const float* __restrict__ beta,
                     float* __restrict__ cst,
                     float* __restrict__ out,
                     __hip_bfloat16* __restrict__ hbf,
                     int t) {
  __shared__ __align__(16) float combL[NC];
  __shared__ float red[16][2];
  __shared__ float stat[2];
  const int m = blockIdx.x, tid = threadIdx.x;

  f32x4 cv = *(const f32x4*)(comb + (size_t)m * NC + tid * 4);
  *(f32x4*)(combL + tid * 4) = cv;
  float s  = cv[0] + cv[1] + cv[2] + cv[3];
  float ss = cv[0] * cv[0] + cv[1] * cv[1] + cv[2] * cv[2] + cv[3] * cv[3];
#pragma unroll
  for (int off = 1; off < 64; off <<= 1) {
    s  += __shfl_xor(s, off);
    ss += __shfl_xor(ss, off);
  }
  const int wid = tid >> 6;
  if ((tid & 63) == 0) { red[wid][0] = s; red[wid][1] = ss; }
  __syncthreads();
  if (tid == 0) {
    float s2 = 0.f, ss2 = 0.f;
#pragma unroll
    for (int i = 0; i < 16; ++i) { s2 += red[i][0]; ss2 += red[i][1]; }
    const float mean = s2 * (1.f / NC);
    const float var  = ss2 * (1.f / NC) - mean * mean;
    stat[0] = mean;
    stat[1] = rsqrtf(var + LN_EPS);
  }
  __syncthreads();
  const float mean = stat[0], rs = stat[1];
  const int j = tid;
  const float iv = (combL[j]          - mean) * rs * gamma[j]          + beta[j];
  const float fv = (combL[NO + j]     - mean) * rs * gamma[NO + j]     + beta[NO + j];
  const float gv = (combL[2 * NO + j] - mean) * rs * gamma[2 * NO + j] + beta[2 * NO + j];
  const float ov = (combL[3 * NO + j] - mean) * rs * gamma[3 * NO + j] + beta[3 * NO + j];
  const float cold = cst[(size_t)m * NO + j];
  const float cc = sigf(fv) * cold + sigf(iv) * tanhf(gv);
  const float hh = sigf(ov) * cc;
  cst[(size_t)m * NO + j] = cc;
  out[((size_t)m * NS + t) * NO + j] = hh;
  hbf[(size_t)m * NO + j] = __float2bfloat16(hh);
}

// ---------------- fallback (small ws): round-1 fp32 path ----------------

__launch_bounds__(256)
__global__ void step_gemm_f32(const float* __restrict__ x, const float* __restrict__ hf,
                              const float* __restrict__ W, const float* __restrict__ bias,
                              float* __restrict__ comb, int t) {
  const int blk = blockIdx.x;
  const int tid = threadIdx.x;
  const int n   = blk * 16 + (tid & 15);
  const int mlo = tid >> 4;
  float a0 = 0.f, a1 = 0.f;
  for (int k = 0; k < NI; ++k) {
    const float wv = W[(size_t)k * NC + n];
    a0 += x[((size_t)mlo * NS + t) * NI + k] * wv;
    a1 += x[((size_t)(mlo + 16) * NS + t) * NI + k] * wv;
  }
  for (int k = 0; k < NO; ++k) {
    const float wv = W[(size_t)(NI + k) * NC + n];
    a0 += hf[mlo * NO + k] * wv;
    a1 += hf[(mlo + 16) * NO + k] * wv;
  }
  comb[(size_t)mlo * NC + n] = a0 + bias[n];
  comb[(size_t)(mlo + 16) * NC + n] = a1 + bias[n];
}

__global__ __launch_bounds__(1024)
void step_update_row_f32(const float* __restrict__ comb,
                         const float* __restrict__ gamma,
                         const float* __restrict__ beta,
                         float* __restrict__ cst,
                         float* __restrict__ out,
                         float* __restrict__ hf,
                         int t) {
  __shared__ __align__(16) float combL[NC];
  __shared__ float red[16][2];
  __shared__ float stat[2];
  const int m = blockIdx.x, tid = threadIdx.x;
  f32x4 cv = *(const f32x4*)(comb + (size_t)m * NC + tid * 4);
  *(f32x4*)(combL + tid * 4) = cv;
  float s  = cv[0] + cv[1] + cv[2] + cv[3];
  float ss = cv[0] * cv[0] + cv[1] * cv[1] + cv[2] * cv[2] + cv[3] * cv[3];
#pragma unroll
  for (int off = 1; off < 64; off <<= 1) {
    s  += __shfl_xor(s, off);
    ss += __shfl_xor(ss, off);
  }
  const int wid = tid >> 6;
  if ((tid & 63) == 0) { red[wid][0] = s; red[wid][1] = ss; }
  __syncthreads();
  if (tid == 0) {
    float s2 = 0.f, ss2 = 0.f;
    for (int i = 0; i < 16; ++i) { s2 += red[i][0]; ss2 += red[i][1]; }
    const float mean = s2 * (1.f / NC);
    const float var  = ss2 * (1.f / NC) - mean * mean;
    stat[0] = mean;
    stat[1] = rsqrtf(var + LN_EPS);
  }
  __syncthreads();
  const float mean = stat[0], rs = stat[1];
  const int j = tid;
  const float iv = (combL[j]          - mean) * rs * gamma[j]          + beta[j];
  const float fv = (combL[NO + j]     - mean) * rs * gamma[NO + j]     + beta[NO + j];
  const float gv = (combL[2 * NO + j] - mean) * rs * gamma[2 * NO + j] + beta[2 * NO + j];
  const float ov = (combL[3 * NO + j] - mean) * rs * gamma[3 * NO + j] + beta[3 * NO + j];
  const float cold = cst[(size_t)m * NO + j];
  const float cc = sigf(fv) * cold + sigf(iv) * tanhf(gv);
  const float hh = sigf(ov) * cc;
  cst[(size_t)m * NO + j] = cc;
  out[((size_t)m * NS + t) * NO + j] = hh;
  hf[(size_t)m * NO + j] = hh;
}

// ---------------- launch ----------------

extern "C" void kernel_launch(void* const* d_in, const int* in_sizes, int n_in,
                              void* d_out, int out_size, void* d_ws, size_t ws_size,
                              hipStream_t stream) {
  (void)in_sizes; (void)n_in; (void)out_size;
  const float* x     = (const float*)d_in[0];
  const float* W     = (const float*)d_in[1];
  const float* bias  = (const float*)d_in[2];
  const float* gamma = (const float*)d_in[3];
  const float* beta  = (const float*)d_in[4];
  const float* hx0   = (const float*)d_in[5];
  const float* cx0   = (const float*)d_in[6];
  float* outp = (float*)d_out;

  char* ws = (char*)d_ws;
  size_t off = 0;
  auto alloc = [&](size_t bytes) -> char* {
    off = (off + 255) & ~(size_t)255;
    char* p = ws + off;
    off += bytes;
    return p;
  };
  // small buffers first (fallback needs only these)
  float* comb          = (float*)alloc((size_t)NB * NC * 4);       // 512KB
  float* cst           = (float*)alloc((size_t)NB * NO * 4);       // 128KB
  float* hf            = (float*)alloc((size_t)NB * NO * 4);       // 128KB
  __hip_bfloat16* hbf  = (__hip_bfloat16*)alloc((size_t)NB * NO * 2);
  // big buffers
  __hip_bfloat16* xbf  = (__hip_bfloat16*)alloc((size_t)NB * NS * NI * 2);  // 16.8MB
  __hip_bfloat16* WF   = (__hip_bfloat16*)alloc((size_t)NK * NC * 2);       // 16.8MB
  const bool big = (ws_size >= off);   // ws_size constant -> same path every call

  hipLaunchKernelGGL(init_state, dim3((NB * NO) / 256), dim3(256), 0, stream,
                     hx0, cx0, hbf, cst, hf);
  if (big) {
    hipLaunchKernelGGL(convert_x, dim3((NB * NS * NI) / (256 * 4)), dim3(256), 0, stream,
                       x, xbf);
    hipLaunchKernelGGL(pack_wf, dim3(256 * 64), dim3(64), 0, stream, W, WF);
    for (int t = 0; t < NS; ++t) {
      hipLaunchKernelGGL(step_gemm_mfma, dim3(256), dim3(256), 0, stream,
                         xbf, hbf, WF, bias, comb, t);
      hipLaunchKernelGGL(step_update_row, dim3(NB), dim3(1024), 0, stream,
                         comb, gamma, beta, cst, outp, hbf, t);
    }
  } else {
    for (int t = 0; t < NS; ++t) {
      hipLaunchKernelGGL(step_gemm_f32, dim3(256), dim3(256), 0, stream,
                         x, hf, W, bias, comb, t);
      hipLaunchKernelGGL(step_update_row_f32, dim3(NB), dim3(1024), 0, stream,
                         comb, gamma, beta, cst, outp, hf, t);
    }
  }
}

// Round 4
// 2445.706 us; speedup vs baseline: 8.5768x; 1.2584x over previous
//
#include <hip/hip_runtime.h>
#include <hip/hip_bf16.h>

#define NB 32      // batch
#define NS 256     // seq len
#define NI 1024    // input size
#define NO 1024    // hidden size
#define NK 2048    // NI + NO
#define NC 4096    // 4 * NO
#define LN_EPS 1e-5f

typedef __attribute__((ext_vector_type(4))) float f32x4;
typedef __attribute__((ext_vector_type(4))) unsigned int u32x4;

__device__ __forceinline__ f32x4 mfma_bf16_16x16x32(u32x4 a, u32x4 b, f32x4 c) {
  asm volatile("v_mfma_f32_16x16x32_bf16 %0, %1, %2, %0" : "+v"(c) : "v"(a), "v"(b));
  return c;
}

__device__ __forceinline__ float sigf(float x) { return 1.0f / (1.0f + __expf(-x)); }
// tanh(x) = 1 - 2/(e^{2x}+1); exp overflow -> inf -> 1, underflow -> 0 -> -1. Both correct.
__device__ __forceinline__ float tanhfast(float x) {
  return 1.0f - 2.0f / (__expf(2.0f * x) + 1.0f);
}

// ---------------- setup kernels ----------------

// x fp32 [m][t][k] -> xfrag bf16 in MFMA A-fragment order:
// xfrag[((t*32 + kt)*2 + plane)*512 + l*8 + j] = x[m=plane*16+(l&15)][t][kt*32+(l>>4)*8+j]
// grid (256 t, 32 kt) x 128 thr.
__global__ void pack_x(const float* __restrict__ x, __hip_bfloat16* __restrict__ xfrag) {
  const int t = blockIdx.x, kt = blockIdx.y;
  const int tid = threadIdx.x;
  const int plane = tid >> 6, l = tid & 63, q = (l >> 4), ln = l & 15;
  const int m = plane * 16 + ln;
  const float* src = x + ((size_t)m * NS + t) * NI + kt * 32 + q * 8;
  float4 v0 = *(const float4*)src;
  float4 v1 = *(const float4*)(src + 4);
  __align__(16) __hip_bfloat16 tmp[8];
  tmp[0] = __float2bfloat16(v0.x); tmp[1] = __float2bfloat16(v0.y);
  tmp[2] = __float2bfloat16(v0.z); tmp[3] = __float2bfloat16(v0.w);
  tmp[4] = __float2bfloat16(v1.x); tmp[5] = __float2bfloat16(v1.y);
  tmp[6] = __float2bfloat16(v1.z); tmp[7] = __float2bfloat16(v1.w);
  *(u32x4*)(xfrag + (((size_t)t * 32 + kt) * 2 + plane) * 512 + l * 8) = *(const u32x4*)tmp;
}

// W fp32 [k=2048][n=4096] -> WF bf16 in MFMA-fragment order (round-3 verified).
__global__ void pack_wf(const float* __restrict__ W, __hip_bfloat16* __restrict__ WF) {
  const int blk = blockIdx.x;
  const int b = blk >> 6, kt = blk & 63;
  const int l = threadIdx.x, q = l >> 4, c = l & 15;
  const int n  = ((c >> 2) << 10) + b * 4 + (c & 3);
  const int k0 = kt * 32 + q * 8;
  __align__(16) __hip_bfloat16 tmp[8];
#pragma unroll
  for (int j = 0; j < 8; ++j)
    tmp[j] = __float2bfloat16(W[(size_t)(k0 + j) * NC + n]);
  *(u32x4*)(WF + ((size_t)(b * 64 + kt) * 64 + l) * 8) = *(const u32x4*)tmp;
}

// hfrag index for h[m][j] (A-fragment order, 2 planes of 16 rows):
__device__ __forceinline__ size_t hfrag_idx(int m, int j) {
  const int kt = j >> 5, q = (j >> 3) & 3, jj = j & 7;
  const int plane = m >> 4, l = q * 16 + (m & 15);
  return (((size_t)kt * 2 + plane) * 64 + l) * 8 + jj;
}

// init h (fragment order + fp32) and c from init_hx/init_cx (broadcast row 0)
__global__ void init_state(const float* __restrict__ hx0, const float* __restrict__ cx0,
                           __hip_bfloat16* __restrict__ hfrag, float* __restrict__ cst,
                           float* __restrict__ hf) {
  const int i = blockIdx.x * 256 + threadIdx.x;  // 32768 = NB*NO
  const int m = i >> 10, j = i & (NO - 1);
  const float hv = hx0[j];
  hfrag[hfrag_idx(m, j)] = __float2bfloat16(hv);
  hf[i]  = hv;
  cst[i] = cx0[j];
}

// ---------------- per-step kernel A: MFMA GEMM ----------------
// grid 256 x 512 (8 waves, 2/SIMD). Block b owns 16 interleaved n-cols
// n(c) = (c>>2)*1024 + b*4 + (c&3). Wave wv covers K-tiles [wv*8, wv*8+8):
// waves 0..3 read xfrag (x part, K<1024), waves 4..7 read hfrag. All loads
// (A and B) are contiguous 16B/lane. K-partials reduced via 16KB LDS.
__global__ __launch_bounds__(512)
void step_gemm_mfma(const __hip_bfloat16* __restrict__ xfrag,
                    const __hip_bfloat16* __restrict__ hfrag,
                    const __hip_bfloat16* __restrict__ WF,
                    const float* __restrict__ bias,
                    float* __restrict__ comb, int t) {
  __shared__ __align__(16) float xch[8 * 2 * 256];   // 16KB
  const int b = blockIdx.x, tid = threadIdx.x;
  const int wv = tid >> 6, l = tid & 63;

  const __hip_bfloat16* ap = (wv < 4)
      ? xfrag + ((size_t)t * 32 + wv * 8) * 1024 + l * 8
      : hfrag + ((size_t)(wv - 4) * 8) * 1024 + l * 8;
  const __hip_bfloat16* bp = WF + ((size_t)(b * 64 + wv * 8) * 64 + l) * 8;

  f32x4 acc0 = {0.f, 0.f, 0.f, 0.f}, acc1 = {0.f, 0.f, 0.f, 0.f};
  asm volatile("s_nop 1" ::);  // VALU-write(acc init) -> MFMA-read-C hazard
#pragma unroll
  for (int i = 0; i < 8; ++i) {
    u32x4 a0 = *(const u32x4*)(ap + (size_t)i * 1024);        // plane 0 (rows 0..15)
    u32x4 a1 = *(const u32x4*)(ap + (size_t)i * 1024 + 512);  // plane 1 (rows 16..31)
    u32x4 bb = *(const u32x4*)(bp + (size_t)i * 512);
    acc0 = mfma_bf16_16x16x32(a0, bb, acc0);
    acc1 = mfma_bf16_16x16x32(a1, bb, acc1);
  }
  asm volatile("s_nop 7\n\ts_nop 7" ::);  // MFMA-write -> VALU-read hazard

  *(f32x4*)(xch + (wv * 2 + 0) * 256 + l * 4) = acc0;
  *(f32x4*)(xch + (wv * 2 + 1) * 256 + l * 4) = acc1;
  __syncthreads();

  // thread -> (row=tid>>4, c=tid&15); D layout: lane=(rr>>2)*16+c, reg=rr&3
  const int row = tid >> 4, c = tid & 15;
  const int p = row >> 4, rr = row & 15;
  const int idx = ((rr >> 2) * 16 + c) * 4 + (rr & 3);
  const int n = ((c >> 2) << 10) + b * 4 + (c & 3);
  float v = bias[n];
#pragma unroll
  for (int w = 0; w < 8; ++w) v += xch[(w * 2 + p) * 256 + idx];
  comb[(size_t)row * NC + n] = v;
}

// ---------------- per-step kernel B: LN + gates + state ----------------
// grid 32 x 1024. Block = batch row m. Block-local LN stats, gates, c/h
// update; writes h in fragment order for next step's GEMM.
__global__ __launch_bounds__(1024)
void step_update_row(const float* __restrict__ comb,
                     const float* __restrict__ gamma,
                     const float* __restrict__ beta,
                     float* __restrict__ cst,
                     float* __restrict__ out,
                     __hip_bfloat16* __restrict__ hfrag,
                     int t) {
  __shared__ __align__(16) float combL[NC];
  __shared__ float red[16][2];
  __shared__ float stat[2];
  const int m = blockIdx.x, tid = threadIdx.x;

  f32x4 cv = *(const f32x4*)(comb + (size_t)m * NC + tid * 4);
  *(f32x4*)(combL + tid * 4) = cv;
  float s  = cv[0] + cv[1] + cv[2] + cv[3];
  float ss = cv[0] * cv[0] + cv[1] * cv[1] + cv[2] * cv[2] + cv[3] * cv[3];
#pragma unroll
  for (int off = 1; off < 64; off <<= 1) {
    s  += __shfl_xor(s, off);
    ss += __shfl_xor(ss, off);
  }
  const int wid = tid >> 6;
  if ((tid & 63) == 0) { red[wid][0] = s; red[wid][1] = ss; }
  __syncthreads();
  if (tid == 0) {
    float s2 = 0.f, ss2 = 0.f;
#pragma unroll
    for (int i = 0; i < 16; ++i) { s2 += red[i][0]; ss2 += red[i][1]; }
    const float mean = s2 * (1.f / NC);
    const float var  = ss2 * (1.f / NC) - mean * mean;
    stat[0] = mean;
    stat[1] = rsqrtf(var + LN_EPS);
  }
  __syncthreads();
  const float mean = stat[0], rs = stat[1];
  const int j = tid;
  const float iv = (combL[j]          - mean) * rs * gamma[j]          + beta[j];
  const float fv = (combL[NO + j]     - mean) * rs * gamma[NO + j]     + beta[NO + j];
  const float gv = (combL[2 * NO + j] - mean) * rs * gamma[2 * NO + j] + beta[2 * NO + j];
  const float ov = (combL[3 * NO + j] - mean) * rs * gamma[3 * NO + j] + beta[3 * NO + j];
  const float cold = cst[(size_t)m * NO + j];
  const float cc = sigf(fv) * cold + sigf(iv) * tanhfast(gv);
  const float hh = sigf(ov) * cc;
  cst[(size_t)m * NO + j] = cc;
  out[((size_t)m * NS + t) * NO + j] = hh;
  hfrag[hfrag_idx(m, j)] = __float2bfloat16(hh);
}

// ---------------- fallback (small ws): fp32 path ----------------

__launch_bounds__(256)
__global__ void step_gemm_f32(const float* __restrict__ x, const float* __restrict__ hf,
                              const float* __restrict__ W, const float* __restrict__ bias,
                              float* __restrict__ comb, int t) {
  const int blk = blockIdx.x;
  const int tid = threadIdx.x;
  const int n   = blk * 16 + (tid & 15);
  const int mlo = tid >> 4;
  float a0 = 0.f, a1 = 0.f;
  for (int k = 0; k < NI; ++k) {
    const float wv = W[(size_t)k * NC + n];
    a0 += x[((size_t)mlo * NS + t) * NI + k] * wv;
    a1 += x[((size_t)(mlo + 16) * NS + t) * NI + k] * wv;
  }
  for (int k = 0; k < NO; ++k) {
    const float wv = W[(size_t)(NI + k) * NC + n];
    a0 += hf[mlo * NO + k] * wv;
    a1 += hf[(mlo + 16) * NO + k] * wv;
  }
  comb[(size_t)mlo * NC + n] = a0 + bias[n];
  comb[(size_t)(mlo + 16) * NC + n] = a1 + bias[n];
}

__global__ __launch_bounds__(1024)
void step_update_row_f32(const float* __restrict__ comb,
                         const float* __restrict__ gamma,
                         const float* __restrict__ beta,
                         float* __restrict__ cst,
                         float* __restrict__ out,
                         float* __restrict__ hf,
                         int t) {
  __shared__ __align__(16) float combL[NC];
  __shared__ float red[16][2];
  __shared__ float stat[2];
  const int m = blockIdx.x, tid = threadIdx.x;
  f32x4 cv = *(const f32x4*)(comb + (size_t)m * NC + tid * 4);
  *(f32x4*)(combL + tid * 4) = cv;
  float s  = cv[0] + cv[1] + cv[2] + cv[3];
  float ss = cv[0] * cv[0] + cv[1] * cv[1] + cv[2] * cv[2] + cv[3] * cv[3];
#pragma unroll
  for (int off = 1; off < 64; off <<= 1) {
    s  += __shfl_xor(s, off);
    ss += __shfl_xor(ss, off);
  }
  const int wid = tid >> 6;
  if ((tid & 63) == 0) { red[wid][0] = s; red[wid][1] = ss; }
  __syncthreads();
  if (tid == 0) {
    float s2 = 0.f, ss2 = 0.f;
    for (int i = 0; i < 16; ++i) { s2 += red[i][0]; ss2 += red[i][1]; }
    const float mean = s2 * (1.f / NC);
    const float var  = ss2 * (1.f / NC) - mean * mean;
    stat[0] = mean;
    stat[1] = rsqrtf(var + LN_EPS);
  }
  __syncthreads();
  const float mean = stat[0], rs = stat[1];
  const int j = tid;
  const float iv = (combL[j]          - mean) * rs * gamma[j]          + beta[j];
  const float fv = (combL[NO + j]     - mean) * rs * gamma[NO + j]     + beta[NO + j];
  const float gv = (combL[2 * NO + j] - mean) * rs * gamma[2 * NO + j] + beta[2 * NO + j];
  const float ov = (combL[3 * NO + j] - mean) * rs * gamma[3 * NO + j] + beta[3 * NO + j];
  const float cold = cst[(size_t)m * NO + j];
  const float cc = sigf(fv) * cold + sigf(iv) * tanhfast(gv);
  const float hh = sigf(ov) * cc;
  cst[(size_t)m * NO + j] = cc;
  out[((size_t)m * NS + t) * NO + j] = hh;
  hf[(size_t)m * NO + j] = hh;
}

// ---------------- launch ----------------

extern "C" void kernel_launch(void* const* d_in, const int* in_sizes, int n_in,
                              void* d_out, int out_size, void* d_ws, size_t ws_size,
                              hipStream_t stream) {
  (void)in_sizes; (void)n_in; (void)out_size;
  const float* x     = (const float*)d_in[0];
  const float* W     = (const float*)d_in[1];
  const float* bias  = (const float*)d_in[2];
  const float* gamma = (const float*)d_in[3];
  const float* beta  = (const float*)d_in[4];
  const float* hx0   = (const float*)d_in[5];
  const float* cx0   = (const float*)d_in[6];
  float* outp = (float*)d_out;

  char* ws = (char*)d_ws;
  size_t off = 0;
  auto alloc = [&](size_t bytes) -> char* {
    off = (off + 255) & ~(size_t)255;
    char* p = ws + off;
    off += bytes;
    return p;
  };
  // small buffers first (fallback needs only these)
  float* comb          = (float*)alloc((size_t)NB * NC * 4);        // 512KB
  float* cst           = (float*)alloc((size_t)NB * NO * 4);        // 128KB
  float* hf            = (float*)alloc((size_t)NB * NO * 4);        // 128KB
  __hip_bfloat16* hfrag = (__hip_bfloat16*)alloc((size_t)NB * NO * 2);  // 64KB
  // big buffers
  __hip_bfloat16* xfrag = (__hip_bfloat16*)alloc((size_t)NB * NS * NI * 2);  // 16.8MB
  __hip_bfloat16* WF    = (__hip_bfloat16*)alloc((size_t)NK * NC * 2);       // 16.8MB
  const bool big = (ws_size >= off);   // ws_size constant -> same path every call

  hipLaunchKernelGGL(init_state, dim3((NB * NO) / 256), dim3(256), 0, stream,
                     hx0, cx0, hfrag, cst, hf);
  if (big) {
    hipLaunchKernelGGL(pack_x, dim3(NS, 32), dim3(128), 0, stream, x, xfrag);
    hipLaunchKernelGGL(pack_wf, dim3(256 * 64), dim3(64), 0, stream, W, WF);
    for (int t = 0; t < NS; ++t) {
      hipLaunchKernelGGL(step_gemm_mfma, dim3(256), dim3(512), 0, stream,
                         xfrag, hfrag, WF, bias, comb, t);
      hipLaunchKernelGGL(step_update_row, dim3(NB), dim3(1024), 0, stream,
                         comb, gamma, beta, cst, outp, hfrag, t);
    }
  } else {
    for (int t = 0; t < NS; ++t) {
      hipLaunchKernelGGL(step_gemm_f32, dim3(256), dim3(256), 0, stream,
                         x, hf, W, bias, comb, t);
      hipLaunchKernelGGL(step_update_row_f32, dim3(NB), dim3(1024), 0, stream,
                         comb, gamma, beta, cst, outp, hf, t);
    }
  }
}